// Round 6
// baseline (123.808 us; speedup 1.0000x reference)
//
#include <hip/hip_runtime.h>
#include <hip/hip_bf16.h>

#define B_ 2
#define R_ 1
#define A_ 16
#define S_ 14
#define F_ 1024
#define N_ 512
#define D_ (S_*N_)        // 7168
#define M_ (B_*R_*A_)     // 32
#define KK_ (2*D_)        // 14336
#define BE 64
#define ETILES (D_/BE)    // 112

typedef __attribute__((ext_vector_type(8))) short bf16x8;
typedef __attribute__((ext_vector_type(4))) float f32x4;

static __device__ inline short f2bf(float f) {
    __hip_bfloat16 h = __float2bfloat16(f);
    return *reinterpret_cast<short*>(&h);
}
static __device__ inline float bf2f(short s) {
    unsigned int u = ((unsigned int)(unsigned short)s) << 16;
    return __uint_as_float(u);
}

#define LDSP(p) ((__attribute__((address_space(3))) void*)(p))
#define GLBP(p) ((const __attribute__((address_space(1))) void*)(p))

// Build packed A' in 16B-unit-transposed layout: Ap unit g=k/8 holds rows 0..63,
// i.e. Ap[(g*64 + r)*8 + (k&7)]. rows 0..31: [yr|yi], rows 32..63: [yi|-yr]
__global__ void prep_kernel(const float* __restrict__ xr, const float* __restrict__ xi,
                            const int* __restrict__ sc, short* __restrict__ Ap) {
    int idx = blockIdx.x * blockDim.x + threadIdx.x;
    if (idx >= 64 * KK_) return;
    int k = idx % KK_;
    int r = idx / KK_;
    int m = r & 31;
    int half = (k >= D_) ? 1 : 0;
    int d = half ? (k - D_) : k;
    int s = d >> 9;
    int n = d & 511;
    int f = sc[n];
    const float* base = (r < 32) ? (half ? xi : xr) : (half ? xr : xi);
    float v = base[(m * S_ + s) * F_ + f];
    if (r >= 32 && half) v = -v;
    Ap[((size_t)(k >> 3) * 64 + r) * 8 + (k & 7)] = f2bf(v);
}

__global__ void zero_kernel(float4* __restrict__ out, int n4) {
    int i = blockIdx.x * blockDim.x + threadIdx.x;
    if (i < n4) out[i] = make_float4(0.f, 0.f, 0.f, 0.f);
}

// -------- wave-autonomous GEMM: zero barriers, per-wave LDS + counted vmcnt ------
// Each wave: 16 output cols (C rows) + private copy of the 64-row A chunk.
// All staging via global_load_lds (proven). No s_barrier anywhere.
__global__ __launch_bounds__(256) void gemm_wasync(
    const short* __restrict__ Ap,
    const float* __restrict__ Cre, const float* __restrict__ Cim,
    short* __restrict__ part_all)
{
    constexpr int KSPLIT = 28;
    constexpr int KBLK = KK_ / KSPLIT;  // 512
    constexpr int NCH  = KBLK / 32;     // 16
    __shared__ float Bl[4][3][16 * 32]; // 24 KB: per-wave 3-buf B tile (swizzled)
    __shared__ short Al[4][3][64 * 32]; // 48 KB: per-wave 3-buf A chunk [g][row][8]

    const int etile = blockIdx.x;
    const int ks    = blockIdx.y;
    const int tid   = threadIdx.x;
    const int wave  = tid >> 6;
    const int lane  = tid & 63;
    const int l16   = lane & 15;
    const int kg    = lane >> 4;

    const float* Cp = (ks < 14) ? Cre : Cim;
    const int kc = (ks % 14) * KBLK;    // col base within C half
    const int ka = ks * KBLK;           // k base in packed A'

    // B staging (wave-private, 2 instr/chunk): unit U = q*64+lane, row=U>>3,
    // stored unit u' = U&7, source unit u = u'^(row&7)  (XOR involution per row)
    const int U0 = lane, U1 = 64 + lane;
    const float* bsrc0 = Cp + (size_t)(etile * 64 + wave * 16 + (U0 >> 3)) * D_
                            + kc + ((U0 & 7) ^ ((U0 >> 3) & 7)) * 4;
    const float* bsrc1 = Cp + (size_t)(etile * 64 + wave * 16 + (U1 >> 3)) * D_
                            + kc + ((U1 & 7) ^ ((U1 >> 3) & 7)) * 4;
    // A staging (4 instr/chunk, linear): source unit (ka/8 + c*4 + q)*64 + lane
    const short* asrc = Ap + (size_t)(ka >> 3) * 512 + lane * 8;

#define WAITV(n) asm volatile("s_waitcnt vmcnt(" #n ")" ::: "memory")
#define STAGE(cc) do { \
        int bb = (cc) % 3; \
        __builtin_amdgcn_global_load_lds(GLBP(bsrc0 + (size_t)(cc) * 32), \
                                         LDSP(&Bl[wave][bb][lane * 4]), 16, 0, 0); \
        __builtin_amdgcn_global_load_lds(GLBP(bsrc1 + (size_t)(cc) * 32), \
                                         LDSP(&Bl[wave][bb][(64 + lane) * 4]), 16, 0, 0); \
        __builtin_amdgcn_global_load_lds(GLBP(asrc + (size_t)(cc) * 2048 + 0 * 512), \
                                         LDSP(&Al[wave][bb][lane * 8]), 16, 0, 0); \
        __builtin_amdgcn_global_load_lds(GLBP(asrc + (size_t)(cc) * 2048 + 1 * 512), \
                                         LDSP(&Al[wave][bb][(64 + lane) * 8]), 16, 0, 0); \
        __builtin_amdgcn_global_load_lds(GLBP(asrc + (size_t)(cc) * 2048 + 2 * 512), \
                                         LDSP(&Al[wave][bb][(128 + lane) * 8]), 16, 0, 0); \
        __builtin_amdgcn_global_load_lds(GLBP(asrc + (size_t)(cc) * 2048 + 3 * 512), \
                                         LDSP(&Al[wave][bb][(192 + lane) * 8]), 16, 0, 0); \
    } while (0)

    STAGE(0);
    STAGE(1);
    STAGE(2);

    f32x4 acc0 = {0.f,0.f,0.f,0.f}, acc1 = {0.f,0.f,0.f,0.f};
    f32x4 acc2 = {0.f,0.f,0.f,0.f}, acc3 = {0.f,0.f,0.f,0.f};

    const int swz  = l16 & 7;
    const int boff = l16 * 32;
    const int u0x = ((kg * 2 + 0) ^ swz) * 4;
    const int u1x = ((kg * 2 + 1) ^ swz) * 4;

    for (int c = 0; c < NCH; ++c) {
        // wait for chunk c's 6 staging ops (per-wave vmcnt; 6 ops per later chunk)
        if (c <= NCH - 3)      { WAITV(12); }
        else if (c == NCH - 2) { WAITV(6); }
        else                   { WAITV(0); }
        __builtin_amdgcn_sched_barrier(0);

        const int buf = c % 3;
        f32x4 b0 = *reinterpret_cast<const f32x4*>(&Bl[wave][buf][boff + u0x]);
        f32x4 b1 = *reinterpret_cast<const f32x4*>(&Bl[wave][buf][boff + u1x]);
        bf16x8 a0 = *reinterpret_cast<const bf16x8*>(&Al[wave][buf][(kg * 64 + 0 * 16 + l16) * 8]);
        bf16x8 a1 = *reinterpret_cast<const bf16x8*>(&Al[wave][buf][(kg * 64 + 1 * 16 + l16) * 8]);
        bf16x8 a2 = *reinterpret_cast<const bf16x8*>(&Al[wave][buf][(kg * 64 + 2 * 16 + l16) * 8]);
        bf16x8 a3 = *reinterpret_cast<const bf16x8*>(&Al[wave][buf][(kg * 64 + 3 * 16 + l16) * 8]);
        asm volatile("s_waitcnt lgkmcnt(0)" ::: "memory");
        __builtin_amdgcn_sched_barrier(0);

        if (c + 3 < NCH) STAGE(c + 3);   // overwrites buf (c+3)%3 == c%3 (just read)
        __builtin_amdgcn_sched_barrier(0);

        bf16x8 bfv;
        bfv[0] = f2bf(b0.x); bfv[1] = f2bf(b0.y); bfv[2] = f2bf(b0.z); bfv[3] = f2bf(b0.w);
        bfv[4] = f2bf(b1.x); bfv[5] = f2bf(b1.y); bfv[6] = f2bf(b1.z); bfv[7] = f2bf(b1.w);
        acc0 = __builtin_amdgcn_mfma_f32_16x16x32_bf16(a0, bfv, acc0, 0, 0, 0);
        acc1 = __builtin_amdgcn_mfma_f32_16x16x32_bf16(a1, bfv, acc1, 0, 0, 0);
        acc2 = __builtin_amdgcn_mfma_f32_16x16x32_bf16(a2, bfv, acc2, 0, 0, 0);
        acc3 = __builtin_amdgcn_mfma_f32_16x16x32_bf16(a3, bfv, acc3, 0, 0, 0);
    }
#undef STAGE
#undef WAITV

    const int e_lane = etile * 64 + wave * 16 + l16;
    short* part = part_all + (size_t)ks * (64 * D_);
    #pragma unroll
    for (int mt = 0; mt < 4; ++mt) {
        f32x4 a = (mt == 0) ? acc0 : (mt == 1) ? acc1 : (mt == 2) ? acc2 : acc3;
        int rbase = mt * 16 + kg * 4;       // D-frag: row=(lane>>4)*4+reg, col=lane&15
        #pragma unroll
        for (int r = 0; r < 4; ++r)
            part[(size_t)(rbase + r) * D_ + e_lane] = f2bf(a[r]);
    }
}

// ---------------- fallback (R4-style, sync, for small workspace) ----------------
template<int KSPLIT, int PARTIALS>
__global__ __launch_bounds__(256) void gemm_sync(
    const short* __restrict__ Ap,
    const float* __restrict__ Cre, const float* __restrict__ Cim,
    const int* __restrict__ sc,
    void* __restrict__ outp)
{
    constexpr int KBLK = KK_ / KSPLIT;
    constexpr int NCH  = KBLK / 32;
    __shared__ float Bls[3][64 * 32];
    __shared__ short Als[3][64 * 32];

    const int etile = blockIdx.x;
    const int ks    = blockIdx.y;
    const int tid   = threadIdx.x;
    const int wave  = tid >> 6;
    const int lane  = tid & 63;
    const int l16   = lane & 15;
    const int kg    = lane >> 4;

    const float* Cp = (ks < KSPLIT / 2) ? Cre : Cim;
    const int kc = (ks % (KSPLIT / 2)) * KBLK;
    const int ka = ks * KBLK;

    const float* bsrc[2];
    #pragma unroll
    for (int q = 0; q < 2; ++q) {
        int U = q * 256 + tid;
        int row = U >> 3;
        int u = (U & 7) ^ (row & 7);
        bsrc[q] = Cp + (size_t)(etile * BE + row) * D_ + kc + u * 4;
    }
    const short* asrc = Ap + ((size_t)(ka >> 3) * 64) * 8 + tid * 8;

#define STG(c) do { \
        int bf_ = (c) % 3; \
        __builtin_amdgcn_global_load_lds(GLBP(bsrc[0] + (size_t)(c) * 32), \
                                         LDSP(&Bls[bf_][(0 * 256 + tid) * 4]), 16, 0, 0); \
        __builtin_amdgcn_global_load_lds(GLBP(bsrc[1] + (size_t)(c) * 32), \
                                         LDSP(&Bls[bf_][(1 * 256 + tid) * 4]), 16, 0, 0); \
        __builtin_amdgcn_global_load_lds(GLBP(asrc + (size_t)(c) * 2048), \
                                         LDSP(&Als[bf_][tid * 8]), 16, 0, 0); \
    } while (0)

    STG(0);
    STG(1);

    f32x4 acc0 = {0.f,0.f,0.f,0.f}, acc1 = {0.f,0.f,0.f,0.f};
    f32x4 acc2 = {0.f,0.f,0.f,0.f}, acc3 = {0.f,0.f,0.f,0.f};

    const int row  = wave * 16 + l16;
    const int swz  = row & 7;
    const int boff = row * 32;
    const int u0 = ((kg * 2 + 0) ^ swz) * 4;
    const int u1 = ((kg * 2 + 1) ^ swz) * 4;

    for (int c = 0; c < NCH; ++c) {
        if (c < NCH - 1) asm volatile("s_waitcnt vmcnt(3)" ::: "memory");
        else             asm volatile("s_waitcnt vmcnt(0)" ::: "memory");
        __builtin_amdgcn_sched_barrier(0);
        __builtin_amdgcn_s_barrier();

        const int buf = c % 3;
        f32x4 b0 = *reinterpret_cast<const f32x4*>(&Bls[buf][boff + u0]);
        f32x4 b1 = *reinterpret_cast<const f32x4*>(&Bls[buf][boff + u1]);
        bf16x8 a0 = *reinterpret_cast<const bf16x8*>(&Als[buf][(kg * 64 + 0 * 16 + l16) * 8]);
        bf16x8 a1 = *reinterpret_cast<const bf16x8*>(&Als[buf][(kg * 64 + 1 * 16 + l16) * 8]);
        bf16x8 a2 = *reinterpret_cast<const bf16x8*>(&Als[buf][(kg * 64 + 2 * 16 + l16) * 8]);
        bf16x8 a3 = *reinterpret_cast<const bf16x8*>(&Als[buf][(kg * 64 + 3 * 16 + l16) * 8]);
        asm volatile("s_waitcnt lgkmcnt(0)" ::: "memory");
        __builtin_amdgcn_sched_barrier(0);
        __builtin_amdgcn_s_barrier();

        if (c + 2 < NCH) STG(c + 2);

        bf16x8 bfv;
        bfv[0] = f2bf(b0.x); bfv[1] = f2bf(b0.y); bfv[2] = f2bf(b0.z); bfv[3] = f2bf(b0.w);
        bfv[4] = f2bf(b1.x); bfv[5] = f2bf(b1.y); bfv[6] = f2bf(b1.z); bfv[7] = f2bf(b1.w);
        acc0 = __builtin_amdgcn_mfma_f32_16x16x32_bf16(a0, bfv, acc0, 0, 0, 0);
        acc1 = __builtin_amdgcn_mfma_f32_16x16x32_bf16(a1, bfv, acc1, 0, 0, 0);
        acc2 = __builtin_amdgcn_mfma_f32_16x16x32_bf16(a2, bfv, acc2, 0, 0, 0);
        acc3 = __builtin_amdgcn_mfma_f32_16x16x32_bf16(a3, bfv, acc3, 0, 0, 0);
    }
#undef STG

    const int e_lane = etile * BE + row;
    if (PARTIALS) {
        short* part = (short*)outp + (size_t)ks * (64 * D_);
        #pragma unroll
        for (int mt = 0; mt < 4; ++mt) {
            f32x4 a = (mt == 0) ? acc0 : (mt == 1) ? acc1 : (mt == 2) ? acc2 : acc3;
            int rbase = mt * 16 + kg * 4;
            #pragma unroll
            for (int r = 0; r < 4; ++r)
                part[(size_t)(rbase + r) * D_ + e_lane] = f2bf(a[r]);
        }
    } else {
        float* out = (float*)outp;
        int s = e_lane >> 9, n = e_lane & 511;
        int f = sc[n];
        #pragma unroll
        for (int mt = 0; mt < 4; ++mt) {
            f32x4 a = (mt == 0) ? acc0 : (mt == 1) ? acc1 : (mt == 2) ? acc2 : acc3;
            int rbase = mt * 16 + kg * 4;
            #pragma unroll
            for (int r = 0; r < 4; ++r) {
                int rr = rbase + r;
                int pp = rr >> 5, m = rr & 31;
                atomicAdd(&out[((pp * M_ + m) * S_ + s) * F_ + f], a[r]);
            }
        }
    }
}

// Sum KSPLIT bf16 partials (8 e-elements per thread), scatter into [2,B,R,A,S,F]
template<int KSPLIT>
__global__ void reduce_kernel(const short* __restrict__ part, const int* __restrict__ sc,
                              float* __restrict__ out) {
    int t = blockIdx.x * blockDim.x + threadIdx.x;
    if (t >= 64 * D_ / 8) return;
    int base = t * 8;
    int e0 = base % D_;
    int r  = base / D_;
    float v[8] = {0.f,0.f,0.f,0.f,0.f,0.f,0.f,0.f};
    #pragma unroll
    for (int ksp = 0; ksp < KSPLIT; ++ksp) {
        bf16x8 x = *reinterpret_cast<const bf16x8*>(&part[(size_t)ksp * (64 * D_) + base]);
        #pragma unroll
        for (int j = 0; j < 8; ++j) v[j] += bf2f(x[j]);
    }
    int pp = r >> 5, m = r & 31, s = e0 >> 9, n0 = e0 & 511;
    float* ob = &out[((pp * M_ + m) * S_ + s) * F_];
    #pragma unroll
    for (int j = 0; j < 8; ++j) ob[sc[n0 + j]] = v[j];
}

extern "C" void kernel_launch(void* const* d_in, const int* in_sizes, int n_in,
                              void* d_out, int out_size, void* d_ws, size_t ws_size,
                              hipStream_t stream) {
    const float* xr  = (const float*)d_in[0];
    const float* xi  = (const float*)d_in[1];
    const float* Cre = (const float*)d_in[2];
    const float* Cim = (const float*)d_in[3];
    const int*   sc  = (const int*)d_in[4];
    float* out = (float*)d_out;

    short* Ap = (short*)d_ws;
    const size_t partOff = 2u * 1024u * 1024u;
    const size_t need28  = partOff + 28ull * 64 * D_ * 2;
    const size_t need16  = partOff + 16ull * 64 * D_ * 2;

    prep_kernel<<<dim3((64 * KK_ + 255) / 256), 256, 0, stream>>>(xr, xi, sc, Ap);
    zero_kernel<<<dim3((917504 / 4 + 255) / 256), 256, 0, stream>>>((float4*)out, 917504 / 4);

    const int rthreads = 64 * D_ / 8;
    if (ws_size >= need28) {
        short* part = (short*)((char*)d_ws + partOff);
        gemm_wasync<<<dim3(ETILES, 28), 256, 0, stream>>>(Ap, Cre, Cim, part);
        reduce_kernel<28><<<dim3((rthreads + 255) / 256), 256, 0, stream>>>(part, sc, out);
    } else if (ws_size >= need16) {
        short* part = (short*)((char*)d_ws + partOff);
        gemm_sync<16, 1><<<dim3(ETILES, 16), 256, 0, stream>>>(Ap, Cre, Cim, sc, part);
        reduce_kernel<16><<<dim3((rthreads + 255) / 256), 256, 0, stream>>>(part, sc, out);
    } else {
        gemm_sync<16, 0><<<dim3(ETILES, 16), 256, 0, stream>>>(Ap, Cre, Cim, sc, out);
    }
}

// Round 7
// 118.909 us; speedup vs baseline: 1.0412x; 1.0412x over previous
//
#include <hip/hip_runtime.h>
#include <hip/hip_bf16.h>

#define B_ 2
#define R_ 1
#define A_ 16
#define S_ 14
#define F_ 1024
#define N_ 512
#define D_ (S_*N_)        // 7168
#define M_ (B_*R_*A_)     // 32
#define KK_ (2*D_)        // 14336
#define BE 64
#define ETILES (D_/BE)    // 112

typedef __attribute__((ext_vector_type(8))) short bf16x8;
typedef __attribute__((ext_vector_type(4))) float f32x4;

static __device__ inline short f2bf(float f) {
    __hip_bfloat16 h = __float2bfloat16(f);
    return *reinterpret_cast<short*>(&h);
}
static __device__ inline float bf2f(short s) {
    unsigned int u = ((unsigned int)(unsigned short)s) << 16;
    return __uint_as_float(u);
}

#define LDSP(p) ((__attribute__((address_space(3))) void*)(p))
#define GLBP(p) ((const __attribute__((address_space(1))) void*)(p))

// Build packed A' in 16B-unit-transposed layout: Ap[(g*64 + r)*8 + (k&7)], g=k/8.
// rows 0..31: [yr|yi], rows 32..63: [yi|-yr]
__global__ void prep_kernel(const float* __restrict__ xr, const float* __restrict__ xi,
                            const int* __restrict__ sc, short* __restrict__ Ap) {
    int idx = blockIdx.x * blockDim.x + threadIdx.x;
    if (idx >= 64 * KK_) return;
    int k = idx % KK_;
    int r = idx / KK_;
    int m = r & 31;
    int half = (k >= D_) ? 1 : 0;
    int d = half ? (k - D_) : k;
    int s = d >> 9;
    int n = d & 511;
    int f = sc[n];
    const float* base = (r < 32) ? (half ? xi : xr) : (half ? xr : xi);
    float v = base[(m * S_ + s) * F_ + f];
    if (r >= 32 && half) v = -v;
    Ap[((size_t)(k >> 3) * 64 + r) * 8 + (k & 7)] = f2bf(v);
}

__global__ void zero_kernel(float4* __restrict__ out, int n4) {
    int i = blockIdx.x * blockDim.x + threadIdx.x;
    if (i < n4) out[i] = make_float4(0.f, 0.f, 0.f, 0.f);
}

// ---------- A-in-registers GEMM: only B goes through global_load_lds ----------
// Per wave: 16 output cols (C rows), A' block in VGPRs (two 128-VGPR phases),
// B wave-private 3-buf LDS, per-wave counted vmcnt, zero barriers.
__global__ __launch_bounds__(256, 2) void gemm_areg(
    const short* __restrict__ Ap,
    const float* __restrict__ Cre, const float* __restrict__ Cim,
    short* __restrict__ part_all)
{
    constexpr int KSPLIT = 28;
    constexpr int KBLK = KK_ / KSPLIT;  // 512
    constexpr int NCH  = KBLK / 32;     // 16
    __shared__ float Bl[4][3][16 * 32]; // 24 KB: per-wave 3-buf B tile (swizzled)

    const int etile = blockIdx.x;
    const int ks    = blockIdx.y;
    const int tid   = threadIdx.x;
    const int wave  = tid >> 6;
    const int lane  = tid & 63;
    const int l16   = lane & 15;
    const int kg    = lane >> 4;

    const float* Cp = (ks < 14) ? Cre : Cim;
    const int kc = (ks % 14) * KBLK;    // col base within C half
    const int ka = ks * KBLK;           // k base in packed A'

    // B staging (wave-private, 2 instr/chunk): unit U = q*64+lane, row=U>>3,
    // stored unit u' = U&7, source unit u = u'^(row&7)  (XOR involution per row)
    const int U0 = lane, U1 = 64 + lane;
    const float* bsrc0 = Cp + (size_t)(etile * 64 + wave * 16 + (U0 >> 3)) * D_
                            + kc + ((U0 & 7) ^ ((U0 >> 3) & 7)) * 4;
    const float* bsrc1 = Cp + (size_t)(etile * 64 + wave * 16 + (U1 >> 3)) * D_
                            + kc + ((U1 & 7) ^ ((U1 >> 3) & 7)) * 4;
    // A register-load base: lane reads 16B units of the transposed layout
    const short* abase = Ap + (((size_t)(ka >> 3) + kg) * 64 + l16) * 8;

#define WAITV(n) asm volatile("s_waitcnt vmcnt(" #n ")" ::: "memory")
#define STAGE(cc) do { \
        int bb = (cc) % 3; \
        __builtin_amdgcn_global_load_lds(GLBP(bsrc0 + (size_t)(cc) * 32), \
                                         LDSP(&Bl[wave][bb][lane * 4]), 16, 0, 0); \
        __builtin_amdgcn_global_load_lds(GLBP(bsrc1 + (size_t)(cc) * 32), \
                                         LDSP(&Bl[wave][bb][(64 + lane) * 4]), 16, 0, 0); \
    } while (0)

    f32x4 acc0 = {0.f,0.f,0.f,0.f}, acc1 = {0.f,0.f,0.f,0.f};
    f32x4 acc2 = {0.f,0.f,0.f,0.f}, acc3 = {0.f,0.f,0.f,0.f};

    const int swz  = l16 & 7;
    const int boff = l16 * 32;
    const int u0x = ((kg * 2 + 0) ^ swz) * 4;
    const int u1x = ((kg * 2 + 1) ^ swz) * 4;

    bf16x8 areg[8][4];

    // ---- phase 0: A regs for chunks 0..7 (plain loads, L2-hot), then fence ----
    #pragma unroll
    for (int c8 = 0; c8 < 8; ++c8)
        #pragma unroll
        for (int mt = 0; mt < 4; ++mt)
            areg[c8][mt] = *reinterpret_cast<const bf16x8*>(abase + (size_t)c8 * 2048 + mt * 128);
    asm volatile("s_waitcnt vmcnt(0)" ::: "memory");
    __builtin_amdgcn_sched_barrier(0);

    STAGE(0);
    STAGE(1);
    STAGE(2);

    #pragma unroll
    for (int c = 0; c < 8; ++c) {
        WAITV(4);                                    // chunk c's 2 B ops done
        __builtin_amdgcn_sched_barrier(0);
        const int buf = c % 3;
        f32x4 b0 = *reinterpret_cast<const f32x4*>(&Bl[wave][buf][boff + u0x]);
        f32x4 b1 = *reinterpret_cast<const f32x4*>(&Bl[wave][buf][boff + u1x]);
        asm volatile("s_waitcnt lgkmcnt(0)" ::: "memory");
        __builtin_amdgcn_sched_barrier(0);
        STAGE(c + 3);                                // c+3 <= 10 < 16 always here
        __builtin_amdgcn_sched_barrier(0);
        bf16x8 bfv;
        bfv[0] = f2bf(b0.x); bfv[1] = f2bf(b0.y); bfv[2] = f2bf(b0.z); bfv[3] = f2bf(b0.w);
        bfv[4] = f2bf(b1.x); bfv[5] = f2bf(b1.y); bfv[6] = f2bf(b1.z); bfv[7] = f2bf(b1.w);
        acc0 = __builtin_amdgcn_mfma_f32_16x16x32_bf16(areg[c][0], bfv, acc0, 0, 0, 0);
        acc1 = __builtin_amdgcn_mfma_f32_16x16x32_bf16(areg[c][1], bfv, acc1, 0, 0, 0);
        acc2 = __builtin_amdgcn_mfma_f32_16x16x32_bf16(areg[c][2], bfv, acc2, 0, 0, 0);
        acc3 = __builtin_amdgcn_mfma_f32_16x16x32_bf16(areg[c][3], bfv, acc3, 0, 0, 0);
    }

    // ---- phase boundary: reload A regs for chunks 8..15; drains B 8,9,10 too
    // (they become LDS-resident; pipeline re-primes below)
    #pragma unroll
    for (int c8 = 0; c8 < 8; ++c8)
        #pragma unroll
        for (int mt = 0; mt < 4; ++mt)
            areg[c8][mt] = *reinterpret_cast<const bf16x8*>(abase + (size_t)(8 + c8) * 2048 + mt * 128);
    asm volatile("s_waitcnt vmcnt(0)" ::: "memory");
    __builtin_amdgcn_sched_barrier(0);

    #pragma unroll
    for (int c = 8; c < 16; ++c) {
        // chunks 8..10 already resident (drained); 11..15 staged at c-3
        if (c <= 13)      { WAITV(4); }
        else if (c == 14) { WAITV(2); }
        else              { WAITV(0); }
        __builtin_amdgcn_sched_barrier(0);
        const int buf = c % 3;
        f32x4 b0 = *reinterpret_cast<const f32x4*>(&Bl[wave][buf][boff + u0x]);
        f32x4 b1 = *reinterpret_cast<const f32x4*>(&Bl[wave][buf][boff + u1x]);
        asm volatile("s_waitcnt lgkmcnt(0)" ::: "memory");
        __builtin_amdgcn_sched_barrier(0);
        if (c + 3 < NCH) STAGE(c + 3);
        __builtin_amdgcn_sched_barrier(0);
        bf16x8 bfv;
        bfv[0] = f2bf(b0.x); bfv[1] = f2bf(b0.y); bfv[2] = f2bf(b0.z); bfv[3] = f2bf(b0.w);
        bfv[4] = f2bf(b1.x); bfv[5] = f2bf(b1.y); bfv[6] = f2bf(b1.z); bfv[7] = f2bf(b1.w);
        acc0 = __builtin_amdgcn_mfma_f32_16x16x32_bf16(areg[c - 8][0], bfv, acc0, 0, 0, 0);
        acc1 = __builtin_amdgcn_mfma_f32_16x16x32_bf16(areg[c - 8][1], bfv, acc1, 0, 0, 0);
        acc2 = __builtin_amdgcn_mfma_f32_16x16x32_bf16(areg[c - 8][2], bfv, acc2, 0, 0, 0);
        acc3 = __builtin_amdgcn_mfma_f32_16x16x32_bf16(areg[c - 8][3], bfv, acc3, 0, 0, 0);
    }
#undef STAGE
#undef WAITV

    const int e_lane = etile * 64 + wave * 16 + l16;
    short* part = part_all + (size_t)ks * (64 * D_);
    #pragma unroll
    for (int mt = 0; mt < 4; ++mt) {
        f32x4 a = (mt == 0) ? acc0 : (mt == 1) ? acc1 : (mt == 2) ? acc2 : acc3;
        int rbase = mt * 16 + kg * 4;       // D-frag: row=(lane>>4)*4+reg, col=lane&15
        #pragma unroll
        for (int r = 0; r < 4; ++r)
            part[(size_t)(rbase + r) * D_ + e_lane] = f2bf(a[r]);
    }
}

// ---------------- fallback (R4-style, sync, for small workspace) ----------------
template<int KSPLIT, int PARTIALS>
__global__ __launch_bounds__(256) void gemm_sync(
    const short* __restrict__ Ap,
    const float* __restrict__ Cre, const float* __restrict__ Cim,
    const int* __restrict__ sc,
    void* __restrict__ outp)
{
    constexpr int KBLK = KK_ / KSPLIT;
    constexpr int NCH  = KBLK / 32;
    __shared__ float Bls[3][64 * 32];
    __shared__ short Als[3][64 * 32];

    const int etile = blockIdx.x;
    const int ks    = blockIdx.y;
    const int tid   = threadIdx.x;
    const int wave  = tid >> 6;
    const int lane  = tid & 63;
    const int l16   = lane & 15;
    const int kg    = lane >> 4;

    const float* Cp = (ks < KSPLIT / 2) ? Cre : Cim;
    const int kc = (ks % (KSPLIT / 2)) * KBLK;
    const int ka = ks * KBLK;

    const float* bsrc[2];
    #pragma unroll
    for (int q = 0; q < 2; ++q) {
        int U = q * 256 + tid;
        int row = U >> 3;
        int u = (U & 7) ^ (row & 7);
        bsrc[q] = Cp + (size_t)(etile * BE + row) * D_ + kc + u * 4;
    }
    const short* asrc = Ap + ((size_t)(ka >> 3) * 64) * 8 + tid * 8;

#define STG(c) do { \
        int bf_ = (c) % 3; \
        __builtin_amdgcn_global_load_lds(GLBP(bsrc[0] + (size_t)(c) * 32), \
                                         LDSP(&Bls[bf_][(0 * 256 + tid) * 4]), 16, 0, 0); \
        __builtin_amdgcn_global_load_lds(GLBP(bsrc[1] + (size_t)(c) * 32), \
                                         LDSP(&Bls[bf_][(1 * 256 + tid) * 4]), 16, 0, 0); \
        __builtin_amdgcn_global_load_lds(GLBP(asrc + (size_t)(c) * 2048), \
                                         LDSP(&Als[bf_][tid * 8]), 16, 0, 0); \
    } while (0)

    STG(0);
    STG(1);

    f32x4 acc0 = {0.f,0.f,0.f,0.f}, acc1 = {0.f,0.f,0.f,0.f};
    f32x4 acc2 = {0.f,0.f,0.f,0.f}, acc3 = {0.f,0.f,0.f,0.f};

    const int row  = wave * 16 + l16;
    const int swz  = row & 7;
    const int boff = row * 32;
    const int u0 = ((kg * 2 + 0) ^ swz) * 4;
    const int u1 = ((kg * 2 + 1) ^ swz) * 4;

    for (int c = 0; c < NCH; ++c) {
        if (c < NCH - 1) asm volatile("s_waitcnt vmcnt(3)" ::: "memory");
        else             asm volatile("s_waitcnt vmcnt(0)" ::: "memory");
        __builtin_amdgcn_sched_barrier(0);
        __builtin_amdgcn_s_barrier();

        const int buf = c % 3;
        f32x4 b0 = *reinterpret_cast<const f32x4*>(&Bls[buf][boff + u0]);
        f32x4 b1 = *reinterpret_cast<const f32x4*>(&Bls[buf][boff + u1]);
        bf16x8 a0 = *reinterpret_cast<const bf16x8*>(&Als[buf][(kg * 64 + 0 * 16 + l16) * 8]);
        bf16x8 a1 = *reinterpret_cast<const bf16x8*>(&Als[buf][(kg * 64 + 1 * 16 + l16) * 8]);
        bf16x8 a2 = *reinterpret_cast<const bf16x8*>(&Als[buf][(kg * 64 + 2 * 16 + l16) * 8]);
        bf16x8 a3 = *reinterpret_cast<const bf16x8*>(&Als[buf][(kg * 64 + 3 * 16 + l16) * 8]);
        asm volatile("s_waitcnt lgkmcnt(0)" ::: "memory");
        __builtin_amdgcn_sched_barrier(0);
        __builtin_amdgcn_s_barrier();

        if (c + 2 < NCH) STG(c + 2);

        bf16x8 bfv;
        bfv[0] = f2bf(b0.x); bfv[1] = f2bf(b0.y); bfv[2] = f2bf(b0.z); bfv[3] = f2bf(b0.w);
        bfv[4] = f2bf(b1.x); bfv[5] = f2bf(b1.y); bfv[6] = f2bf(b1.z); bfv[7] = f2bf(b1.w);
        acc0 = __builtin_amdgcn_mfma_f32_16x16x32_bf16(a0, bfv, acc0, 0, 0, 0);
        acc1 = __builtin_amdgcn_mfma_f32_16x16x32_bf16(a1, bfv, acc1, 0, 0, 0);
        acc2 = __builtin_amdgcn_mfma_f32_16x16x32_bf16(a2, bfv, acc2, 0, 0, 0);
        acc3 = __builtin_amdgcn_mfma_f32_16x16x32_bf16(a3, bfv, acc3, 0, 0, 0);
    }
#undef STG

    const int e_lane = etile * BE + row;
    if (PARTIALS) {
        short* part = (short*)outp + (size_t)ks * (64 * D_);
        #pragma unroll
        for (int mt = 0; mt < 4; ++mt) {
            f32x4 a = (mt == 0) ? acc0 : (mt == 1) ? acc1 : (mt == 2) ? acc2 : acc3;
            int rbase = mt * 16 + kg * 4;
            #pragma unroll
            for (int r = 0; r < 4; ++r)
                part[(size_t)(rbase + r) * D_ + e_lane] = f2bf(a[r]);
        }
    } else {
        float* out = (float*)outp;
        int s = e_lane >> 9, n = e_lane & 511;
        int f = sc[n];
        #pragma unroll
        for (int mt = 0; mt < 4; ++mt) {
            f32x4 a = (mt == 0) ? acc0 : (mt == 1) ? acc1 : (mt == 2) ? acc2 : acc3;
            int rbase = mt * 16 + kg * 4;
            #pragma unroll
            for (int r = 0; r < 4; ++r) {
                int rr = rbase + r;
                int pp = rr >> 5, m = rr & 31;
                atomicAdd(&out[((pp * M_ + m) * S_ + s) * F_ + f], a[r]);
            }
        }
    }
}

// Sum KSPLIT bf16 partials (8 e-elements per thread), scatter into [2,B,R,A,S,F]
template<int KSPLIT>
__global__ void reduce_kernel(const short* __restrict__ part, const int* __restrict__ sc,
                              float* __restrict__ out) {
    int t = blockIdx.x * blockDim.x + threadIdx.x;
    if (t >= 64 * D_ / 8) return;
    int base = t * 8;
    int e0 = base % D_;
    int r  = base / D_;
    float v[8] = {0.f,0.f,0.f,0.f,0.f,0.f,0.f,0.f};
    #pragma unroll
    for (int ksp = 0; ksp < KSPLIT; ++ksp) {
        bf16x8 x = *reinterpret_cast<const bf16x8*>(&part[(size_t)ksp * (64 * D_) + base]);
        #pragma unroll
        for (int j = 0; j < 8; ++j) v[j] += bf2f(x[j]);
    }
    int pp = r >> 5, m = r & 31, s = e0 >> 9, n0 = e0 & 511;
    float* ob = &out[((pp * M_ + m) * S_ + s) * F_];
    #pragma unroll
    for (int j = 0; j < 8; ++j) ob[sc[n0 + j]] = v[j];
}

extern "C" void kernel_launch(void* const* d_in, const int* in_sizes, int n_in,
                              void* d_out, int out_size, void* d_ws, size_t ws_size,
                              hipStream_t stream) {
    const float* xr  = (const float*)d_in[0];
    const float* xi  = (const float*)d_in[1];
    const float* Cre = (const float*)d_in[2];
    const float* Cim = (const float*)d_in[3];
    const int*   sc  = (const int*)d_in[4];
    float* out = (float*)d_out;

    short* Ap = (short*)d_ws;
    const size_t partOff = 2u * 1024u * 1024u;
    const size_t need28  = partOff + 28ull * 64 * D_ * 2;
    const size_t need16  = partOff + 16ull * 64 * D_ * 2;

    prep_kernel<<<dim3((64 * KK_ + 255) / 256), 256, 0, stream>>>(xr, xi, sc, Ap);
    zero_kernel<<<dim3((917504 / 4 + 255) / 256), 256, 0, stream>>>((float4*)out, 917504 / 4);

    const int rthreads = 64 * D_ / 8;
    if (ws_size >= need28) {
        short* part = (short*)((char*)d_ws + partOff);
        gemm_areg<<<dim3(ETILES, 28), 256, 0, stream>>>(Ap, Cre, Cim, part);
        reduce_kernel<28><<<dim3((rthreads + 255) / 256), 256, 0, stream>>>(part, sc, out);
    } else if (ws_size >= need16) {
        short* part = (short*)((char*)d_ws + partOff);
        gemm_sync<16, 1><<<dim3(ETILES, 16), 256, 0, stream>>>(Ap, Cre, Cim, sc, part);
        reduce_kernel<16><<<dim3((rthreads + 255) / 256), 256, 0, stream>>>(part, sc, out);
    } else {
        gemm_sync<16, 0><<<dim3(ETILES, 16), 256, 0, stream>>>(Ap, Cre, Cim, sc, out);
    }
}